// Round 13
// baseline (452.009 us; speedup 1.0000x reference)
//
#include <hip/hip_runtime.h>

// EntityLinker fused edge-MLP for MI355X (gfx950).
// Round 13: async weight prefetch via global_load_lds + fine vmcnt(N).
//   R12 falsified the occupancy play (22->44% occ gave -8%): waves convoy on
//   per-iteration vmcnt(0) B-waits. The compiler discards register prefetch
//   (R3/R8b), so use the DMA path it can't sink:
//   - B staged wave-private into LDS double buffers by global_load_lds
//     (R11's fragment-major packing = 1KB contiguous per frag, the exact
//     wave-uniform-base + lane*16B addressing the DMA requires).
//   - K-loops have NO barriers and wait s_waitcnt vmcnt(4)/(2), never 0
//     except at loop end (AITER pattern).
//   - M=64, 2 WG/CU, LDS 68KB. Keeps bf16 node cache + staged diff/prod.

#define H 128

typedef __bf16 bf16x8 __attribute__((ext_vector_type(8)));
typedef float f32x4 __attribute__((ext_vector_type(4)));

typedef __attribute__((address_space(1))) const unsigned int gu32;
typedef __attribute__((address_space(3))) unsigned int lu32;

// async 16B/lane global->LDS DMA; lds base must be wave-uniform (HW scatters
// lane i to base + i*16).
__device__ __forceinline__ void dma16(const unsigned short* g, unsigned short* ldsBase) {
    __builtin_amdgcn_global_load_lds((gu32*)g, (lu32*)ldsBase, 16, 0, 0);
}
template <int N>
__device__ __forceinline__ void wait_vm() {
    __builtin_amdgcn_s_waitcnt(0xF70 | N);   // lgkm=15, exp=7, vmcnt=N
    asm volatile("" ::: "memory");
}
__device__ __forceinline__ void membar() { asm volatile("" ::: "memory"); }

__device__ __forceinline__ unsigned short f2bf(float f) {
    unsigned u = __builtin_bit_cast(unsigned, f);
    u += 0x7FFFu + ((u >> 16) & 1u);   // RNE
    return (unsigned short)(u >> 16);
}
__device__ __forceinline__ float bfhi(unsigned u) {
    return __builtin_bit_cast(float, u & 0xffff0000u);
}
__device__ __forceinline__ float bflo(unsigned u) {
    return __builtin_bit_cast(float, u << 16);
}
__device__ __forceinline__ unsigned pk2(float r0, float r1) {
    unsigned u0 = __builtin_bit_cast(unsigned, r0) + 0x8000u;
    unsigned u1 = __builtin_bit_cast(unsigned, r1) + 0x8000u;
    return __builtin_amdgcn_perm(u1, u0, 0x07060302u);
}
__device__ __forceinline__ unsigned comb(unsigned ua, unsigned ub, bool isdiff) {
    float a0 = bflo(ua), a1 = bfhi(ua);
    float b0 = bflo(ub), b1 = bfhi(ub);
    float r0 = isdiff ? fabsf(a0 - b0) : a0 * b0;
    float r1 = isdiff ? fabsf(a1 - b1) : a1 * b1;
    return pk2(r0, r1);
}
__device__ __forceinline__ unsigned short cvt1(float v) {
    unsigned u = __builtin_bit_cast(unsigned, v) + 0x8000u;
    return (unsigned short)(u >> 16);
}

__global__ void prep_node(const float* __restrict__ node, unsigned short* __restrict__ nbf) {
    int idx = blockIdx.x * 256 + threadIdx.x;
    const f32x4* p = (const f32x4*)(node) + idx;
    f32x4 v = *p;
    ushort4 w;
    w.x = f2bf(v.x); w.y = f2bf(v.y); w.z = f2bf(v.z); w.w = f2bf(v.w);
    *(ushort4*)(nbf + idx * 4) = w;
}

// Fragment-major pack of W1 [512][256]: W1P[(g_nt*16+ks)*512 + lane*8 + j]
//   = W1[k][row], row = g_nt*16+(lane&15), k = ks*32+(lane>>4)*8+j
__global__ void prep_w1(const float* __restrict__ W1, unsigned short* __restrict__ W1P) {
    int o = blockIdx.x * 256 + threadIdx.x;        // 131072
    int chunk = o >> 9;
    int g_nt = chunk >> 4;
    int ks = chunk & 15;
    int r = o & 511;
    int lane = r >> 3;
    int j = r & 7;
    int row = g_nt * 16 + (lane & 15);
    int k = ks * 32 + (lane >> 4) * 8 + j;
    W1P[o] = f2bf(W1[k * 256 + row]);
}

// Fragment-major pack of W2 [256][128]: W2P[(g_nt*8+ks)*512 + lane*8 + j]
__global__ void prep_w2(const float* __restrict__ W2, unsigned short* __restrict__ W2P) {
    int o = blockIdx.x * 256 + threadIdx.x;        // 32768
    int chunk = o >> 9;
    int g_nt = chunk >> 3;
    int ks = chunk & 7;
    int r = o & 511;
    int lane = r >> 3;
    int j = r & 7;
    int row = g_nt * 16 + (lane & 15);
    int k = ks * 32 + (lane >> 4) * 8 + j;
    W2P[o] = f2bf(W2[k * 128 + row]);
}

__launch_bounds__(256, 2)
__global__ void fused_mlp(const unsigned short* __restrict__ nbf,   // [N][128] bf16
                          const int* __restrict__ src,
                          const int* __restrict__ dst,
                          const unsigned short* __restrict__ W1P,  // packed
                          const float* __restrict__ b1,
                          const unsigned short* __restrict__ W2P,  // packed
                          const float* __restrict__ b2,
                          const float* __restrict__ W3,            // [128][2] f32
                          const float* __restrict__ b3,
                          float* __restrict__ out,                 // [E][2] f32
                          int E) {
    __shared__ __align__(16) unsigned short sH[64 * 268];    // 34304 B
    __shared__ __align__(16) unsigned short sB[2][4][2048];  // 32768 B: [buf][wave][frag<4>*512]
    __shared__ __align__(16) float sW3[256];                 // [c][128]

    const int t = threadIdx.x;
    const int e0 = blockIdx.x * 64;

    const int lane = t & 63;
    const int wv = t >> 6;
    const int quad = lane >> 4;
    const int lrow = lane & 15;
    const int nb = wv * 64;        // layer-1 N-slice
    const int nb2 = wv * 32;       // layer-2 N-slice

    // Per-thread global frag pointers (packed layout): frag (nt, ks) at
    //   w1g + nt*(16*512) + ks*512      (elements; each frag 1KB contiguous)
    const unsigned short* w1g = W1P + (wv * 4) * 16 * 512 + lane * 8;
    const unsigned short* w2g = W2P + (wv * 2) * 8 * 512 + lane * 8;
    unsigned short* sBw0 = &sB[0][wv][0];     // wave-uniform LDS bases
    unsigned short* sBw1 = &sB[1][wv][0];

    // ---- Layer-1 prologue: stage ks=0 -> buf0, ks=1 -> buf1 (async) ----
#pragma unroll
    for (int nt = 0; nt < 4; nt++) dma16(w1g + nt * 8192, sBw0 + nt * 512);
#pragma unroll
    for (int nt = 0; nt < 4; nt++) dma16(w1g + nt * 8192 + 512, sBw1 + nt * 512);

    // ---------------- Phase A: gather hi/hj (bf16) -> LDS ----------------
    {
        int r = t >> 2;            // edge row 0..63
        int q = t & 3;             // 32-col quarter
        int e = e0 + r;
        int ec = e < E ? e : (E - 1);
        const unsigned short* hi = nbf + (long)src[ec] * H + q * 32;
        const unsigned short* hj = nbf + (long)dst[ec] * H + q * 32;
        unsigned short* rowp = sH + r * 268 + q * 32;
#pragma unroll
        for (int b = 0; b < 4; b++) {
            uint4 a = *(const uint4*)(hi + b * 8);
            uint4 c = *(const uint4*)(hj + b * 8);
            *(uint4*)(rowp + b * 8)       = a;
            *(uint4*)(rowp + 136 + b * 8) = c;
        }
        sW3[(t & 1) * 128 + (t >> 1)] = W3[t];   // [k][c] -> [c][k]
    }
    __syncthreads();               // hi/hj visible (also drains S0,S1 DMAs)

    // ---------------- Phase B: layer 1 (M=64, N=256, K=512) ----------------
    f32x4 acc[4][4];
#pragma unroll
    for (int mt = 0; mt < 4; mt++)
#pragma unroll
        for (int nt = 0; nt < 4; nt++)
            acc[mt][nt] = (f32x4){0.f, 0.f, 0.f, 0.f};

    int aoff[4];
#pragma unroll
    for (int mt = 0; mt < 4; mt++) aoff[mt] = (mt * 16 + lrow) * 268 + quad * 8;

    // K-half 1: global ks 0..7 (A = hi | hj). Barrier-free pipelined loop.
#pragma unroll 1
    for (int ks = 0; ks < 8; ks++) {
        if (ks == 7) wait_vm<0>(); else wait_vm<4>();
        const unsigned short* bb = (ks & 1) ? sBw1 : sBw0;
        const int ao = (ks < 4) ? ks * 32 : 136 + (ks - 4) * 32;
        bf16x8 bv[4], av[4];
#pragma unroll
        for (int nt = 0; nt < 4; nt++) bv[nt] = *(const bf16x8*)(bb + nt * 512 + lane * 8);
#pragma unroll
        for (int mt = 0; mt < 4; mt++) av[mt] = *(const bf16x8*)(sH + aoff[mt] + ao);
#pragma unroll
        for (int mt = 0; mt < 4; mt++)
#pragma unroll
            for (int nt = 0; nt < 4; nt++)
                acc[mt][nt] = __builtin_amdgcn_mfma_f32_16x16x32_bf16(av[mt], bv[nt], acc[mt][nt], 0, 0, 0);
        if (ks < 6) {
            membar();              // keep ds_reads above the buffer overwrite
            unsigned short* db = (ks & 1) ? sBw1 : sBw0;
#pragma unroll
            for (int nt = 0; nt < 4; nt++)
                dma16(w1g + nt * 8192 + (ks + 2) * 512, db + nt * 512);
        }
    }

    // ---- Half-2 prologue: stage global ks=8 -> buf0, ks=9 -> buf1 ----
#pragma unroll
    for (int nt = 0; nt < 4; nt++) dma16(w1g + nt * 8192 + 8 * 512, sBw0 + nt * 512);
#pragma unroll
    for (int nt = 0; nt < 4; nt++) dma16(w1g + nt * 8192 + 9 * 512, sBw1 + nt * 512);

    __syncthreads();               // half-1 reads of hi/hj complete (drains DMAs too)

    // ------------- Staging: diff -> region P, prod -> region Q (in place) -------
    {
        int r = t >> 2;
        int c0 = (t & 3) * 32;
        unsigned short* rowp = sH + r * 268;
#pragma unroll
        for (int j = 0; j < 4; j++) {
            uint4 ua = *(const uint4*)(rowp + c0 + j * 8);
            uint4 ub = *(const uint4*)(rowp + 136 + c0 + j * 8);
            uint4 dd, pp;
            dd.x = comb(ua.x, ub.x, true);  dd.y = comb(ua.y, ub.y, true);
            dd.z = comb(ua.z, ub.z, true);  dd.w = comb(ua.w, ub.w, true);
            pp.x = comb(ua.x, ub.x, false); pp.y = comb(ua.y, ub.y, false);
            pp.z = comb(ua.z, ub.z, false); pp.w = comb(ua.w, ub.w, false);
            *(uint2*)(rowp + c0 + j * 8)           = (uint2){dd.x, dd.y};
            *(uint2*)(rowp + c0 + j * 8 + 4)       = (uint2){dd.z, dd.w};
            *(uint2*)(rowp + 136 + c0 + j * 8)     = (uint2){pp.x, pp.y};
            *(uint2*)(rowp + 136 + c0 + j * 8 + 4) = (uint2){pp.z, pp.w};
        }
    }
    __syncthreads();               // diff/prod staged

    // K-half 2: global ks 8..15 (A = diff | prod). Buffers pre-filled.
#pragma unroll 1
    for (int ks = 0; ks < 8; ks++) {
        if (ks == 7) wait_vm<0>(); else wait_vm<4>();
        const unsigned short* bb = (ks & 1) ? sBw1 : sBw0;
        const int ao = (ks < 4) ? ks * 32 : 136 + (ks - 4) * 32;
        bf16x8 bv[4], av[4];
#pragma unroll
        for (int nt = 0; nt < 4; nt++) bv[nt] = *(const bf16x8*)(bb + nt * 512 + lane * 8);
#pragma unroll
        for (int mt = 0; mt < 4; mt++) av[mt] = *(const bf16x8*)(sH + aoff[mt] + ao);
#pragma unroll
        for (int mt = 0; mt < 4; mt++)
#pragma unroll
            for (int nt = 0; nt < 4; nt++)
                acc[mt][nt] = __builtin_amdgcn_mfma_f32_16x16x32_bf16(av[mt], bv[nt], acc[mt][nt], 0, 0, 0);
        if (ks < 6) {
            membar();
            unsigned short* db = (ks & 1) ? sBw1 : sBw0;
#pragma unroll
            for (int nt = 0; nt < 4; nt++)
                dma16(w1g + nt * 8192 + (ks + 10) * 512, db + nt * 512);
        }
    }

    // ---- Layer-2 prologue + bias loads (latency absorbed by phase C) ----
    float b1v[4];
#pragma unroll
    for (int nt = 0; nt < 4; nt++) b1v[nt] = b1[nb + nt * 16 + lrow];
    membar();
#pragma unroll
    for (int nt = 0; nt < 2; nt++) dma16(w2g + nt * 4096, sBw0 + nt * 512);
#pragma unroll
    for (int nt = 0; nt < 2; nt++) dma16(w2g + nt * 4096 + 512, sBw1 + nt * 512);

    // ---------------- Phase C: relu+bias -> x1 bf16 (overlay sH) ----------------
    __syncthreads();               // all layer-1 reads of sH done
    unsigned short* sx1 = sH;      // [64][268], cols 0..255
#pragma unroll
    for (int mt = 0; mt < 4; mt++)
#pragma unroll
        for (int nt = 0; nt < 4; nt++)
#pragma unroll
            for (int i = 0; i < 4; i++) {
                int row = mt * 16 + quad * 4 + i;    // C/D: row = quad*4 + reg
                int col = nb + nt * 16 + lrow;       //      col = lane&15
                float v = acc[mt][nt][i] + b1v[nt];
                v = v > 0.f ? v : 0.f;
                sx1[row * 268 + col] = cvt1(v);
            }
    __syncthreads();               // x1 complete (drains T0,T1 DMAs)

    // ---------------- Phase D: layer 2 (M=64, N=128, K=256), pipelined ----------
    f32x4 acc2[4][2];
#pragma unroll
    for (int mt = 0; mt < 4; mt++)
#pragma unroll
        for (int nt = 0; nt < 2; nt++)
            acc2[mt][nt] = (f32x4){0.f, 0.f, 0.f, 0.f};

#pragma unroll 1
    for (int ks = 0; ks < 8; ks++) {
        if (ks == 7) wait_vm<0>(); else wait_vm<2>();
        const unsigned short* bb = (ks & 1) ? sBw1 : sBw0;
        bf16x8 bv2[2], av2[4];
#pragma unroll
        for (int nt = 0; nt < 2; nt++) bv2[nt] = *(const bf16x8*)(bb + nt * 512 + lane * 8);
#pragma unroll
        for (int mt = 0; mt < 4; mt++) av2[mt] = *(const bf16x8*)(sx1 + aoff[mt] + ks * 32);
#pragma unroll
        for (int mt = 0; mt < 4; mt++)
#pragma unroll
            for (int nt = 0; nt < 2; nt++)
                acc2[mt][nt] = __builtin_amdgcn_mfma_f32_16x16x32_bf16(av2[mt], bv2[nt], acc2[mt][nt], 0, 0, 0);
        if (ks < 6) {
            membar();
            unsigned short* db = (ks & 1) ? sBw1 : sBw0;
#pragma unroll
            for (int nt = 0; nt < 2; nt++)
                dma16(w2g + nt * 4096 + (ks + 2) * 512, db + nt * 512);
        }
    }

    // ---------------- Phase E: relu+bias -> x2 bf16 (overlay) ----------------
    float b2v[2];
#pragma unroll
    for (int nt = 0; nt < 2; nt++) b2v[nt] = b2[nb2 + nt * 16 + lrow];

    __syncthreads();               // all layer-2 reads of x1 done
    unsigned short* sx2 = sH;      // [64][140]
#pragma unroll
    for (int mt = 0; mt < 4; mt++)
#pragma unroll
        for (int nt = 0; nt < 2; nt++)
#pragma unroll
            for (int i = 0; i < 4; i++) {
                int row = mt * 16 + quad * 4 + i;
                int col = nb2 + nt * 16 + lrow;
                float v = acc2[mt][nt][i] + b2v[nt];
                v = v > 0.f ? v : 0.f;
                sx2[row * 140 + col] = cvt1(v);
            }
    __syncthreads();

    // ---------------- Phase F: layer 3 (N=2), half-dots + shfl ----------------
    {
        int r = t >> 2;            // edge row 0..63
        int c = t & 1;             // class
        int h = (t >> 1) & 1;      // K-half
        const unsigned short* xr = sx2 + r * 140 + h * 64;
        const float* w3c = sW3 + c * 128 + h * 64;
        float s = 0.f;
#pragma unroll
        for (int j = 0; j < 8; j++) {
            uint4 v = *(const uint4*)(xr + j * 8);
            const float* w = w3c + j * 8;
            s += bflo(v.x) * w[0] + bfhi(v.x) * w[1]
               + bflo(v.y) * w[2] + bfhi(v.y) * w[3]
               + bflo(v.z) * w[4] + bfhi(v.z) * w[5]
               + bflo(v.w) * w[6] + bfhi(v.w) * w[7];
        }
        s += __shfl_xor(s, 2);     // combine K-halves
        int e = e0 + r;
        if (h == 0 && e < E) out[e * 2 + c] = s + b3[c];
    }
}

extern "C" void kernel_launch(void* const* d_in, const int* in_sizes, int n_in,
                              void* d_out, int out_size, void* d_ws, size_t ws_size,
                              hipStream_t stream) {
    const float* node = (const float*)d_in[0];
    const int* src    = (const int*)d_in[1];
    const int* dst    = (const int*)d_in[2];
    const float* W1   = (const float*)d_in[3];
    const float* b1   = (const float*)d_in[4];
    const float* W2   = (const float*)d_in[5];
    const float* b2   = (const float*)d_in[6];
    const float* W3   = (const float*)d_in[7];
    const float* b3   = (const float*)d_in[8];
    float* out = (float*)d_out;
    const int NN = in_sizes[0] / H;                    // 50000 nodes
    const int E = in_sizes[1];

    unsigned short* W1P = (unsigned short*)d_ws;       // packed W1, 256 KiB
    unsigned short* W2P = W1P + 512 * 256;             // packed W2, 64 KiB
    unsigned short* NBF = W2P + 256 * 128;             // [N][128] bf16, 12.8 MB

    hipLaunchKernelGGL(prep_node, dim3((NN * H / 4 + 255) / 256), dim3(256), 0, stream, node, NBF);
    hipLaunchKernelGGL(prep_w1, dim3(512), dim3(256), 0, stream, W1, W1P);
    hipLaunchKernelGGL(prep_w2, dim3(128), dim3(256), 0, stream, W2, W2P);
    const int nblk = (E + 63) / 64;
    hipLaunchKernelGGL(fused_mlp, dim3(nblk), dim3(256), 0, stream,
                       NBF, src, dst, W1P, b1, W2P, b2, W3, b3, out, E);
}